// Round 5
// baseline (295.740 us; speedup 1.0000x reference)
//
#include <hip/hip_runtime.h>

#define Tq 4096
#define Dq 1024
#define NCOL 2048      // 512 (z) + 512 (zq) + 1024 (v), all bf16 in one buffer
#define RIDGEC 1e-3f
#define PSTRIDE 4104   // per-(chunk,bh) part slice: 4096 sums + 1 max (+pad)

typedef float  f4_t  __attribute__((ext_vector_type(4)));
typedef __bf16 bf8_t __attribute__((ext_vector_type(8)));
typedef unsigned short us4_t __attribute__((ext_vector_type(4)));

typedef __attribute__((address_space(1))) const void* gas_t;
typedef __attribute__((address_space(3))) void* sas_t;

__device__ __forceinline__ unsigned short f2bf(float f){
    unsigned int u = __float_as_uint(f);
    u += 0x7fffu + ((u >> 16) & 1u);        // RNE
    return (unsigned short)(u >> 16);
}
__device__ __forceinline__ float bf2f(unsigned short u){
    return __uint_as_float(((unsigned int)u) << 16);
}

// ---------------- prep: h -> bf16 (blocks 0..16383), W concat -> bf16 (blocks 16384..18431) ----------------
__global__ __launch_bounds__(256) void k_prep(const float* __restrict__ h,
                                              const float* __restrict__ Wk,
                                              const float* __restrict__ Wq,
                                              const float* __restrict__ Wv,
                                              unsigned short* __restrict__ hbf,
                                              unsigned short* __restrict__ wbf){
    int bx = blockIdx.x;
    if (bx < 16384){
        size_t i = ((size_t)bx*256 + threadIdx.x)*4;
        float4 v = *(const float4*)(h + i);
        us4_t o; o.x=f2bf(v.x); o.y=f2bf(v.y); o.z=f2bf(v.z); o.w=f2bf(v.w);
        *(us4_t*)(hbf + i) = o;
    } else {
        size_t i = ((size_t)(bx - 16384)*256 + threadIdx.x)*4;
        int row = (int)(i >> 10), col = (int)(i & 1023);
        const float* s;
        if (row < 512)       s = Wk + (size_t)row*1024 + col;
        else if (row < 1024) s = Wq + (size_t)(row-512)*1024 + col;
        else                 s = Wv + (size_t)(row-1024)*1024 + col;
        float4 v = *(const float4*)s;
        us4_t o; o.x=f2bf(v.x); o.y=f2bf(v.y); o.z=f2bf(v.z); o.w=f2bf(v.w);
        *(us4_t*)(wbf + i) = o;
    }
}

// ---------------- bf16 MFMA GEMM: zqv(16384x2048 bf16) = h @ W^T ----------------
// 256x256 tile, BK=64, 8 waves (2Mx4N). Unit = [128 rows][64 cols] bf16 = 16 KiB,
// 4 units per matrix: [parity][half]. XOR swizzle -> 0 bank conflicts (r2).
// R5: ONE barrier per phase (was 2) so issue-regions overlap MFMA-regions across
// waves; even staging 1 unit/phase; R4's same-parity stage moved AFTER the
// vmcnt+bar (proven WAR-safe: all B(par) reads consumed pre-bar via lgkmcnt).

#define STG(BUF, SRC, PAR, HF, KC) do{ \
    const unsigned short* g_ = (SRC) + (HF)*131072 + (KC); \
    unsigned short* l_ = &BUF[(PAR)*16384 + (HF)*8192 + w*1024]; \
    __builtin_amdgcn_global_load_lds((gas_t)(g_), (sas_t)l_, 16, 0, 0); \
    __builtin_amdgcn_global_load_lds((gas_t)(g_ + 8192), (sas_t)(l_ + 512), 16, 0, 0); \
  }while(0)

#define RDA(MI, CS, PAR)  (*(const bf8_t*)&Abuf[(PAR)*16384 + aBase + (MI)*1024 + (CS)])
#define RDB(NJ, CS, PAR)  (*(const bf8_t*)&Bbuf[(PAR)*16384 + bBase + (NJ)*1024 + (CS)])

#define LDA4(DST, MIB, CS, PAR) do{ \
    _Pragma("unroll") \
    for (int mi_=0; mi_<4; ++mi_) DST[mi_] = RDA((MIB)+mi_, CS, PAR); \
  }while(0)
#define LDB4(DST, CS, PAR) do{ \
    _Pragma("unroll") \
    for (int nj_=0; nj_<4; ++nj_) DST[nj_] = RDB(nj_, CS, PAR); \
  }while(0)

#define BARIN() do{ __builtin_amdgcn_s_barrier(); __builtin_amdgcn_sched_barrier(0); }while(0)

#define MMQ(AFA, BFA, AB) do{ \
    __builtin_amdgcn_s_setprio(1); \
    _Pragma("unroll") \
    for (int mi_=0; mi_<4; ++mi_){ \
      _Pragma("unroll") \
      for (int nj_=0; nj_<4; ++nj_) \
        acc[(AB)+mi_][nj_] = __builtin_amdgcn_mfma_f32_16x16x32_bf16(AFA[mi_], BFA[nj_], acc[(AB)+mi_][nj_], 0, 0, 0); \
    } \
    __builtin_amdgcn_s_setprio(0); \
  }while(0)

__global__ __launch_bounds__(512, 2) void k_gemm(const unsigned short* __restrict__ A,
                                                 const unsigned short* __restrict__ Bw,
                                                 unsigned short* __restrict__ zqv){
    __shared__ __align__(16) unsigned short Abuf[2*2*128*64];   // 64 KiB
    __shared__ __align__(16) unsigned short Bbuf[2*2*128*64];   // 64 KiB
    const int tid = threadIdx.x, w = tid >> 6, lane = tid & 63;
    const int wr = w >> 2, wc = w & 3;                 // 2 x 4 wave grid
    const int bid = blockIdx.x;
    const int swz = (bid & 7)*64 + (bid >> 3);         // XCD-aware (512 % 8 == 0, bijective)
    const int m0 = (swz >> 3)*256, n0 = (swz & 7)*256;

    // ---- stage source: linear LDS dest, inverse-swizzled global source (rule #21)
    const int c0   = w*128 + lane;                     // chunk index within unit
    const int row0 = c0 >> 3;                          // 0..127
    const int swz8 = ((lane & 7) ^ (lane >> 3))*8;     // swizzled col-chunk * 8 elems
    const unsigned short* Asrc = A  + (size_t)(m0 + row0)*Dq + swz8;
    const unsigned short* Bsrc = Bw + (size_t)(n0 + row0)*Dq + swz8;

    // ---- ds_read offsets (ushort), read-side XOR swizzle: chunk ^= row&7
    const int r16 = lane & 15, kg = lane >> 4;
    const int cswz0 = ((kg    ) ^ (r16 & 7))*8;        // ks=0 global chunks 0..3
    const int cswz1 = ((kg + 4) ^ (r16 & 7))*8;        // ks=1 global chunks 4..7
    const int aBase = wr*8192 + r16*64;
    const int bBase = (wc >> 1)*8192 + (wc & 1)*4096 + r16*64;

    f4_t acc[8][4];
#pragma unroll
    for (int i=0;i<8;++i)
#pragma unroll
        for (int j=0;j<4;++j) acc[i][j] = (f4_t){0.f,0.f,0.f,0.f};

    bf8_t aE[4], aO[4], aE2[4], aO2[4], bE[4], bO[4];

    // ---- prologue: tile 0 (4 units) + (1,B,h0); keep only that in flight
    STG(Abuf, Asrc, 0, 0, 0);     // (0,A,h0)
    STG(Abuf, Asrc, 0, 1, 0);     // (0,A,h1)
    STG(Bbuf, Bsrc, 0, 0, 0);     // (0,B,h0)
    STG(Bbuf, Bsrc, 0, 1, 0);     // (0,B,h1)
    STG(Bbuf, Bsrc, 1, 0, 64);    // (1,B,h0)
    asm volatile("s_waitcnt vmcnt(2)" ::: "memory");
    __builtin_amdgcn_s_barrier();
    __builtin_amdgcn_sched_barrier(0);

    // ---- main loop: tiles 0..13, ONE barrier per phase
    for (int t = 0; t < 14; ++t){
        const int par = t & 1, npar = par ^ 1;
        const int kc1 = (t+1)*64, kc2 = (t+2)*64;

        // R1: reads for ph1 (same-region) + ph2; stage (t+1,A,h0)
        LDA4(aE, 0, cswz0, par);
        LDB4(bE, cswz0, par);
        LDA4(aO, 4, cswz0, par);
        STG(Abuf, Asrc, npar, 0, kc1);
        BARIN(); MMQ(aE, bE, 0);

        // R2: reads for ph3; stage (t+1,A,h1)
        LDA4(aE2, 0, cswz1, par);
        LDB4(bO, cswz1, par);
        STG(Abuf, Asrc, npar, 1, kc1);
        BARIN(); MMQ(aO, bE, 4);

        // R3: reads for ph4; stage (t+1,B,h1)
        LDA4(aO2, 4, cswz1, par);
        STG(Bbuf, Bsrc, npar, 1, kc1);
        BARIN(); MMQ(aE2, bO, 0);

        // R4: drain tile t+1's units; stage (t+2,B,h0) into parity par AFTER the
        // bar (B(par) reads consumed by every wave before it reached this bar)
        asm volatile("s_waitcnt vmcnt(0)" ::: "memory");
        BARIN();
        STG(Bbuf, Bsrc, par, 0, kc2);
        MMQ(aO2, bO, 4);
    }

    // ---- tile 14 (par=0): stage tile 15's remaining units, full drain at R4
    {
        const int par = 0, npar = 1, kc1 = 960;
        LDA4(aE, 0, cswz0, par);
        LDB4(bE, cswz0, par);
        LDA4(aO, 4, cswz0, par);
        STG(Abuf, Asrc, npar, 0, kc1);
        BARIN(); MMQ(aE, bE, 0);

        LDA4(aE2, 0, cswz1, par);
        LDB4(bO, cswz1, par);
        STG(Abuf, Asrc, npar, 1, kc1);
        BARIN(); MMQ(aO, bE, 4);

        LDA4(aO2, 4, cswz1, par);
        STG(Bbuf, Bsrc, npar, 1, kc1);
        BARIN(); MMQ(aE2, bO, 0);

        asm volatile("s_waitcnt vmcnt(0)" ::: "memory");
        BARIN();
        MMQ(aO2, bO, 4);
    }

    // ---- tile 15 (par=1): compute-only, no barriers needed
    {
        const int par = 1;
        LDA4(aE, 0, cswz0, par);
        LDB4(bE, cswz0, par);
        MMQ(aE, bE, 0);
        LDA4(aO, 4, cswz0, par);
        MMQ(aO, bE, 4);
        LDA4(aE2, 0, cswz1, par);
        LDB4(bO, cswz1, par);
        MMQ(aE2, bO, 0);
        LDA4(aO2, 4, cswz1, par);
        MMQ(aO2, bO, 4);
    }

    // ---- C write (bf16), verified C/D layout: col=lane&15, row=(lane>>4)*4+q
#pragma unroll
    for (int mi=0;mi<8;++mi){
#pragma unroll
        for (int nj=0;nj<4;++nj){
            const int col = n0 + wc*64 + nj*16 + r16;
            const int rb  = m0 + wr*128 + mi*16 + (lane >> 4)*4;
#pragma unroll
            for (int q=0;q<4;++q)
                zqv[(size_t)(rb+q)*NCOL + col] = f2bf(acc[mi][nj][q]);
        }
    }
}

#undef STG
#undef RDA
#undef RDB
#undef LDA4
#undef LDB4
#undef BARIN
#undef MMQ

// ---------------- G / M_cov / C_v partial sums + per-chunk max||z||^2 ----------------
__global__ __launch_bounds__(256) void k_cov(const unsigned short* __restrict__ zqv,
                                             const float* __restrict__ mask,
                                             float* __restrict__ part){
    __shared__ float Zs[65*32];
    __shared__ float Vs[64*64];
    __shared__ float Msk[66];
    __shared__ float sMx[64];
    const int tid = threadIdx.x, w = tid >> 6, lane = tid & 63;
    const int c = blockIdx.x, bh = blockIdx.y, b = bh >> 4, h = bh & 15;
    const unsigned short* zb = zqv + (size_t)b*Tq*NCOL + h*32;
    const unsigned short* vb = zqv + (size_t)b*Tq*NCOL + 1024 + h*64;
    const float* mb = mask + (size_t)b*Tq;

    const bool isC = lane >= 32;
    const bool isM = (lane >= 16) && (lane < 32);
    const int li = isC ? (lane - 32) : (lane & 15);
    const int i0 = (li >> 2)*8, j0 = (li & 3)*8;
    const float* Xb = isC ? (Vs + i0) : (Zs + 32 + i0);
    const int xst = isC ? 64 : 32;
    const float* Yb = isM ? (Zs + j0) : (Zs + 32 + j0);
    const int slotbase = isC ? (2048 + i0*32 + j0) : ((isM ? 1024 : 0) + i0*32 + j0);

    float acc[8][8];
#pragma unroll
    for (int i=0;i<8;++i)
#pragma unroll
        for (int j=0;j<8;++j) acc[i][j] = 0.f;
    float mxl = 0.f;

    for (int t0 = c*512; t0 < c*512 + 512; t0 += 64){
        __syncthreads();
        for (int i = tid; i < 520; i += 256){
            int r = i >> 3, cc = (i & 7)*4;
            int t = t0 - 1 + r;
            float4 o;
            if (t >= 0){
                us4_t u = *(const us4_t*)(zb + (size_t)t*NCOL + cc);
                o.x = bf2f(u.x); o.y = bf2f(u.y); o.z = bf2f(u.z); o.w = bf2f(u.w);
            } else { o.x=0.f; o.y=0.f; o.z=0.f; o.w=0.f; }
            *(float4*)&Zs[r*32 + cc] = o;
        }
        for (int i = tid; i < 1024; i += 256){
            int rr = i >> 4, cc = (i & 15)*4;
            us4_t u = *(const us4_t*)(vb + (size_t)(t0 + rr)*NCOL + cc);
            float4 o; o.x=bf2f(u.x); o.y=bf2f(u.y); o.z=bf2f(u.z); o.w=bf2f(u.w);
            *(float4*)&Vs[rr*64 + cc] = o;
        }
        if (tid < 65){ int t = t0 - 1 + tid; Msk[tid] = (t >= 0) ? mb[t] : 0.f; }
        __syncthreads();
        if (tid < 64){
            const float4* pr = (const float4*)&Zs[(tid+1)*32];
            float s = 0.f;
#pragma unroll
            for (int q=0;q<8;++q){ float4 v = pr[q]; s += v.x*v.x + v.y*v.y + v.z*v.z + v.w*v.w; }
            mxl = fmaxf(mxl, s);
        }
#pragma unroll 2
        for (int tt = w; tt < 64; tt += 4){
            const float mt = Msk[tt+1], mp = Msk[tt];
            const float m2 = mt*mt, al = mt*mp;
            const float wgt = isM ? (al*al) : m2;
            const float* xp = Xb + tt*xst;
            const float* yp = Yb + tt*32;
            float4 x0 = *(const float4*)xp, x1 = *(const float4*)(xp + 4);
            float4 y0 = *(const float4*)yp, y1 = *(const float4*)(yp + 4);
            float xs[8] = {x0.x*wgt, x0.y*wgt, x0.z*wgt, x0.w*wgt,
                           x1.x*wgt, x1.y*wgt, x1.z*wgt, x1.w*wgt};
            float ys[8] = {y0.x, y0.y, y0.z, y0.w, y1.x, y1.y, y1.z, y1.w};
#pragma unroll
            for (int i=0;i<8;++i)
#pragma unroll
                for (int j=0;j<8;++j) acc[i][j] += xs[i]*ys[j];
        }
    }
    // cross-wave reduce in LDS (reuse Vs: 4096 floats)
    float* Acc = Vs;
    __syncthreads();
    if (tid < 64) sMx[tid] = mxl;
#pragma unroll
    for (int r = 0; r < 4; ++r){
        if (w == r){
            if (r == 0){
#pragma unroll
                for (int i=0;i<8;++i)
#pragma unroll
                    for (int j=0;j<8;++j) Acc[slotbase + i*32 + j] = acc[i][j];
            } else {
#pragma unroll
                for (int i=0;i<8;++i)
#pragma unroll
                    for (int j=0;j<8;++j) Acc[slotbase + i*32 + j] += acc[i][j];
            }
        }
        __syncthreads();
    }
    float* dst = part + ((size_t)c*64 + bh)*PSTRIDE;
    for (int i = tid; i < 4096; i += 256) dst[i] = Acc[i];
    if (tid == 0){
        float m = 0.f;
#pragma unroll
        for (int q=0;q<64;++q) m = fmaxf(m, sMx[q]);
        dst[4096] = m;
    }
}

// ---------------- per-(b,h) fp32 solver (no Cholesky):
// Gi = G^-1 (Gauss-Jordan), P = M Gi, Q = Gi P, sigma^2 = lam_max(M^T Q) via power iter,
// E = eta/mn * s^2 * C (Q P),  s = gam/max(sigma,1); E stored bf16 ----------------
__global__ __launch_bounds__(256) void k_solve(const float* __restrict__ part,
                                               const float* __restrict__ eta_p,
                                               const float* __restrict__ gam_p,
                                               unsigned short* __restrict__ Ebf){
    __shared__ float sM[1024], sC[2048], sGi[1024], sP[1024], sQ[1024], sT[1024];
    __shared__ float sAug[32*66];
    __shared__ float sv[32], su[32], sw[32], ssc[4];
    const int tid = threadIdx.x, bh = blockIdx.x;
    const size_t pb = (size_t)bh*PSTRIDE;

    // max over chunk maxes (redundant per-thread, broadcast loads)
    float mxx = 0.f;
#pragma unroll
    for (int c = 0; c < 8; ++c) mxx = fmaxf(mxx, part[((size_t)c*64)*PSTRIDE + pb + 4096]);
    const float mn = fmaxf(sqrtf(mxx), 1e-6f);
    const float i1 = 1.f/mn, i2 = i1*i1;

    for (int i = tid; i < 1024; i += 256){
        float a0 = 0.f, a1 = 0.f;
        for (int c = 0; c < 8; ++c){
            const float* p = part + ((size_t)c*64)*PSTRIDE + pb;
            a0 += p[i]; a1 += p[1024 + i];
        }
        sT[i] = a0; sM[i] = a1*i2;
    }
    for (int i = tid; i < 2048; i += 256){
        float a = 0.f;
        for (int c = 0; c < 8; ++c) a += part[((size_t)c*64)*PSTRIDE + pb + 2048 + i];
        sC[i] = a*i1;
    }
    __syncthreads();
    // Aug = [G_sym + ridge | I]
    for (int i = tid; i < 1024; i += 256){
        int r = i >> 5, s = i & 31;
        float g = 0.5f*(sT[i] + sT[s*32 + r])*i2 + (r == s ? RIDGEC : 0.f);
        sAug[r*66 + s] = g;
        sAug[r*66 + 32 + s] = (r == s) ? 1.f : 0.f;
    }
    __syncthreads();
    // Gauss-Jordan (SPD, no pivoting)
    const int gi = tid >> 3, gj0 = (tid & 7)*8;
    for (int p = 0; p < 32; ++p){
        float pivd = sAug[p*66 + p];
        float f    = sAug[gi*66 + p];
        float rp[8];
#pragma unroll
        for (int jj = 0; jj < 8; ++jj) rp[jj] = sAug[p*66 + gj0 + jj];
        __syncthreads();
        float pinv = 1.f/pivd;
        if (gi == p){
#pragma unroll
            for (int jj = 0; jj < 8; ++jj) sAug[p*66 + gj0 + jj] = rp[jj]*pinv;
        } else {
            float fp = f*pinv;
#pragma unroll
            for (int jj = 0; jj < 8; ++jj) sAug[gi*66 + gj0 + jj] -= fp*rp[jj];
        }
        __syncthreads();
    }
    for (int i = tid; i < 1024; i += 256){
        int r = i >> 5, s = i & 31;
        sGi[i] = sAug[r*66 + 32 + s];
    }
    __syncthreads();
    // P = M @ Gi   (left-row preload, float4 broadcast on right)
    {
        const int r = tid >> 3, s0 = (tid & 7)*4;
        float lrow[32];
#pragma unroll
        for (int q = 0; q < 8; ++q) *(float4*)&lrow[q*4] = *(const float4*)&sM[r*32 + q*4];
        float4 a = (float4){0.f,0.f,0.f,0.f};
        for (int k = 0; k < 32; ++k){
            float4 bb = *(const float4*)&sGi[k*32 + s0];
            a.x += lrow[k]*bb.x; a.y += lrow[k]*bb.y; a.z += lrow[k]*bb.z; a.w += lrow[k]*bb.w;
        }
        *(float4*)&sP[r*32 + s0] = a;
    }
    __syncthreads();
    // Q = Gi @ P
    {
        const int r = tid >> 3, s0 = (tid & 7)*4;
        float lrow[32];
#pragma unroll
        for (int q = 0; q < 8; ++q) *(float4*)&lrow[q*4] = *(const float4*)&sGi[r*32 + q*4];
        float4 a = (float4){0.f,0.f,0.f,0.f};
        for (int k = 0; k < 32; ++k){
            float4 bb = *(const float4*)&sP[k*32 + s0];
            a.x += lrow[k]*bb.x; a.y += lrow[k]*bb.y; a.z += lrow[k]*bb.z; a.w += lrow[k]*bb.w;
        }
        *(float4*)&sQ[r*32 + s0] = a;
    }
    __syncthreads();
    // power iteration: v <- normalize(M^T (Q v)), 6 iters
    if (tid < 32) sv[tid] = 0.17677669529663687f;
    __syncthreads();
    for (int it = 0; it < 6; ++it){
        if (tid < 32){ float a = 0.f; for (int k = 0; k < 32; ++k) a += sQ[tid*32+k]*sv[k]; su[tid] = a; }
        __syncthreads();
        if (tid < 32){ float a = 0.f; for (int k = 0; k < 32; ++k) a += sM[k*32+tid]*su[k]; sw[tid] = a; }
        __syncthreads();
        if (tid < 32){
            float n2 = 0.f;
#pragma unroll
            for (int k = 0; k < 32; ++k) n2 += sw[k]*sw[k];
            sv[tid] = sw[tid] * (1.f/fmaxf(sqrtf(n2), 1e-8f));
        }
        __syncthreads();
    }
    if (tid < 32){ float a = 0.f; for (int k = 0; k < 32; ++k) a += sQ[tid*32+k]*sv[k]; su[tid] = a; }
    __syncthreads();
    if (tid < 32){ float a = 0.f; for (int k = 0; k < 32; ++k) a += sM[k*32+tid]*su[k]; sw[tid] = a; }
    __syncthreads();
    if (tid == 0){
        float n2 = 0.f;
        for (int k = 0; k < 32; ++k) n2 += sw[k]*sw[k];
        float sigma = sqrtf(sqrtf(n2));          // ||Wv|| = sigma^2
        float gam = fminf(fmaxf(gam_p[0], 1.f), 1.5f);
        float s = gam/fmaxf(sigma, 1.f);
        ssc[0] = eta_p[0]*i1*s*s;
    }
    __syncthreads();
    // T = Q @ P
    {
        const int r = tid >> 3, s0 = (tid & 7)*4;
        float lrow[32];
#pragma unroll
        for (int q = 0; q < 8; ++q) *(float4*)&lrow[q*4] = *(const float4*)&sQ[r*32 + q*4];
        float4 a = (float4){0.f,0.f,0.f,0.f};
        for (int k = 0; k < 32; ++k){
            float4 bb = *(const float4*)&sP[k*32 + s0];
            a.x += lrow[k]*bb.x; a.y += lrow[k]*bb.y; a.z += lrow[k]*bb.z; a.w += lrow[k]*bb.w;
        }
        *(float4*)&sT[r*32 + s0] = a;
    }
    __syncthreads();
    // E = esc * C @ T  (64x32 @ 32x32), stored bf16 row-major (p x r)
    {
        const float esc = ssc[0];
        const int r = tid >> 2, s0 = (tid & 3)*8;
        float lrow[32];
#pragma unroll
        for (int q = 0; q < 8; ++q) *(float4*)&lrow[q*4] = *(const float4*)&sC[r*32 + q*4];
        float4 a0 = (float4){0.f,0.f,0.f,0.f}, a1 = (float4){0.f,0.f,0.f,0.f};
        for (int k = 0; k < 32; ++k){
            float4 b0 = *(const float4*)&sT[k*32 + s0];
            float4 b1 = *(const float4*)&sT[k*32 + s0 + 4];
            a0.x += lrow[k]*b0.x; a0.y += lrow[k]*b0.y; a0.z += lrow[k]*b0.z; a0.w += lrow[k]*b0.w;
            a1.x += lrow[k]*b1.x; a1.y += lrow[k]*b1.y; a1.z += lrow[k]*b1.z; a1.w += lrow[k]*b1.w;
        }
        us4_t o0, o1;
        o0.x=f2bf(a0.x*esc); o0.y=f2bf(a0.y*esc); o0.z=f2bf(a0.z*esc); o0.w=f2bf(a0.w*esc);
        o1.x=f2bf(a1.x*esc); o1.y=f2bf(a1.y*esc); o1.z=f2bf(a1.z*esc); o1.w=f2bf(a1.w*esc);
        *(us4_t*)&Ebf[(size_t)bh*2048 + r*32 + s0]     = o0;
        *(us4_t*)&Ebf[(size_t)bh*2048 + r*32 + s0 + 4] = o1;
    }
}

// ---------------- out[t,p] = sum_r zq[t,r] * E[p,r]  via MFMA (A=zq rows, B=E rows) ----------------
__global__ __launch_bounds__(256) void k_outm(const unsigned short* __restrict__ zqv,
                                              const unsigned short* __restrict__ Ebf,
                                              float* __restrict__ out){
    __shared__ __align__(16) unsigned short Es[2048];
    const int tid = threadIdx.x, w = tid >> 6, lane = tid & 63;
    const int bh = blockIdx.y, b = bh >> 4, h = bh & 15;
    // stage E (64 p x 32 r bf16 = 4096 B)
    ((float4*)Es)[tid & 255] = ((const float4*)(Ebf + (size_t)bh*2048))[tid & 255];
    __syncthreads();

    const int row16 = lane & 15, klo = (lane >> 4)*8;
    const int t0 = blockIdx.x*128 + w*32;
    const unsigned short* zq = zqv + ((size_t)b*Tq + t0 + row16)*NCOL + 512 + h*32 + klo;
    bf8_t aF0 = *(const bf8_t*)zq;
    bf8_t aF1 = *(const bf8_t*)(zq + (size_t)16*NCOL);

    bf8_t bF[4];
#pragma unroll
    for (int j=0;j<4;++j) bF[j] = *(const bf8_t*)&Es[(j*16 + row16)*32 + klo];

    f4_t acc[2][4];
#pragma unroll
    for (int i=0;i<2;++i)
#pragma unroll
        for (int j=0;j<4;++j) acc[i][j] = (f4_t){0.f,0.f,0.f,0.f};
#pragma unroll
    for (int j=0;j<4;++j){
        acc[0][j] = __builtin_amdgcn_mfma_f32_16x16x32_bf16(aF0, bF[j], acc[0][j], 0, 0, 0);
        acc[1][j] = __builtin_amdgcn_mfma_f32_16x16x32_bf16(aF1, bF[j], acc[1][j], 0, 0, 0);
    }
    const int rbase = (lane >> 4)*4;
#pragma unroll
    for (int half=0; half<2; ++half){
#pragma unroll
        for (int j=0;j<4;++j){
            int col = h*64 + j*16 + row16;
#pragma unroll
            for (int q=0;q<4;++q){
                int t = t0 + half*16 + rbase + q;
                out[((size_t)b*Tq + t)*1024 + col] = acc[half][j][q];
            }
        }
    }
}

extern "C" void kernel_launch(void* const* d_in, const int* in_sizes, int n_in,
                              void* d_out, int out_size, void* d_ws, size_t ws_size,
                              hipStream_t stream) {
    const float* h    = (const float*)d_in[0];
    const float* mask = (const float*)d_in[1];
    const float* Wk   = (const float*)d_in[2];
    const float* Wq   = (const float*)d_in[3];
    const float* Wv   = (const float*)d_in[4];
    const float* eta  = (const float*)d_in[5];
    const float* gam  = (const float*)d_in[6];
    float* out = (float*)d_out;

    char* ws = (char*)d_ws;
    unsigned short* hbf = (unsigned short*)(ws);                       // 33,554,432
    unsigned short* wbf = (unsigned short*)(ws + 33554432);            //  4,194,304
    unsigned short* zqv = (unsigned short*)(ws + 37748736);            // 67,108,864
    float*          part= (float*)         (ws + 104857600);           //  8,404,992
    unsigned short* Ebf = (unsigned short*)(ws + 113262592);           //    262,144

    k_prep <<<18432, 256, 0, stream>>>(h, Wk, Wq, Wv, hbf, wbf);
    k_gemm <<<dim3(512), 512, 0, stream>>>(hbf, wbf, zqv);
    k_cov  <<<dim3(8, 64), 256, 0, stream>>>(zqv, mask, part);
    k_solve<<<64, 256, 0, stream>>>(part, eta, gam, Ebf);
    k_outm <<<dim3(32, 64), 256, 0, stream>>>(zqv, Ebf, out);
}

// Round 6
// 294.849 us; speedup vs baseline: 1.0030x; 1.0030x over previous
//
#include <hip/hip_runtime.h>

#define Tq 4096
#define Dq 1024
#define NCOL 2048      // 512 (z) + 512 (zq) + 1024 (v), all bf16 in one buffer
#define RIDGEC 1e-3f
#define PSTRIDE 4104   // per-(chunk,bh) part slice: 4096 sums + 1 max (+pad)

typedef float  f4_t  __attribute__((ext_vector_type(4)));
typedef __bf16 bf8_t __attribute__((ext_vector_type(8)));
typedef unsigned short us4_t __attribute__((ext_vector_type(4)));

typedef __attribute__((address_space(1))) const void* gas_t;
typedef __attribute__((address_space(3))) void* sas_t;

__device__ __forceinline__ unsigned short f2bf(float f){
    unsigned int u = __float_as_uint(f);
    u += 0x7fffu + ((u >> 16) & 1u);        // RNE
    return (unsigned short)(u >> 16);
}
__device__ __forceinline__ float bf2f(unsigned short u){
    return __uint_as_float(((unsigned int)u) << 16);
}

// ---------------- prep: h -> bf16 (blocks 0..16383), W concat -> bf16 (blocks 16384..18431) ----------------
__global__ __launch_bounds__(256) void k_prep(const float* __restrict__ h,
                                              const float* __restrict__ Wk,
                                              const float* __restrict__ Wq,
                                              const float* __restrict__ Wv,
                                              unsigned short* __restrict__ hbf,
                                              unsigned short* __restrict__ wbf){
    int bx = blockIdx.x;
    if (bx < 16384){
        size_t i = ((size_t)bx*256 + threadIdx.x)*4;
        float4 v = *(const float4*)(h + i);
        us4_t o; o.x=f2bf(v.x); o.y=f2bf(v.y); o.z=f2bf(v.z); o.w=f2bf(v.w);
        *(us4_t*)(hbf + i) = o;
    } else {
        size_t i = ((size_t)(bx - 16384)*256 + threadIdx.x)*4;
        int row = (int)(i >> 10), col = (int)(i & 1023);
        const float* s;
        if (row < 512)       s = Wk + (size_t)row*1024 + col;
        else if (row < 1024) s = Wq + (size_t)(row-512)*1024 + col;
        else                 s = Wv + (size_t)(row-1024)*1024 + col;
        float4 v = *(const float4*)s;
        us4_t o; o.x=f2bf(v.x); o.y=f2bf(v.y); o.z=f2bf(v.z); o.w=f2bf(v.w);
        *(us4_t*)(wbf + i) = o;
    }
}

// ---------------- bf16 MFMA GEMM: zqv(16384x2048 bf16) = h @ W^T ----------------
// 256x256 tile, BK=64, 8 waves (2Mx4N). Unit = [128 rows][64 cols] bf16 = 16 KiB,
// 4 units per matrix: [parity][half]. XOR swizzle -> 0 bank conflicts (r2).
// R6: (a) plain s_barrier at R1-R3 (no sched_barrier) -- same-parity reads may
// hoist/interleave with MFMA across those bars (harmless, desired); the ONE true
// hazard boundary (parity flip) keeps vmcnt(0)+bar+sched_barrier at R4.
// (b) staging moved earlier: A h0+h1 at R1, B h1 at R2 -> 2-4 phase cover at drain.

#define STG(BUF, SRC, PAR, HF, KC) do{ \
    const unsigned short* g_ = (SRC) + (HF)*131072 + (KC); \
    unsigned short* l_ = &BUF[(PAR)*16384 + (HF)*8192 + w*1024]; \
    __builtin_amdgcn_global_load_lds((gas_t)(g_), (sas_t)l_, 16, 0, 0); \
    __builtin_amdgcn_global_load_lds((gas_t)(g_ + 8192), (sas_t)(l_ + 512), 16, 0, 0); \
  }while(0)

#define RDA(MI, CS, PAR)  (*(const bf8_t*)&Abuf[(PAR)*16384 + aBase + (MI)*1024 + (CS)])
#define RDB(NJ, CS, PAR)  (*(const bf8_t*)&Bbuf[(PAR)*16384 + bBase + (NJ)*1024 + (CS)])

#define LDA4(DST, MIB, CS, PAR) do{ \
    _Pragma("unroll") \
    for (int mi_=0; mi_<4; ++mi_) DST[mi_] = RDA((MIB)+mi_, CS, PAR); \
  }while(0)
#define LDB4(DST, CS, PAR) do{ \
    _Pragma("unroll") \
    for (int nj_=0; nj_<4; ++nj_) DST[nj_] = RDB(nj_, CS, PAR); \
  }while(0)

#define BAR()  __builtin_amdgcn_s_barrier()
#define BARF() do{ __builtin_amdgcn_s_barrier(); __builtin_amdgcn_sched_barrier(0); }while(0)

#define MMQ(AFA, BFA, AB) do{ \
    __builtin_amdgcn_s_setprio(1); \
    _Pragma("unroll") \
    for (int mi_=0; mi_<4; ++mi_){ \
      _Pragma("unroll") \
      for (int nj_=0; nj_<4; ++nj_) \
        acc[(AB)+mi_][nj_] = __builtin_amdgcn_mfma_f32_16x16x32_bf16(AFA[mi_], BFA[nj_], acc[(AB)+mi_][nj_], 0, 0, 0); \
    } \
    __builtin_amdgcn_s_setprio(0); \
  }while(0)

__global__ __launch_bounds__(512, 2) void k_gemm(const unsigned short* __restrict__ A,
                                                 const unsigned short* __restrict__ Bw,
                                                 unsigned short* __restrict__ zqv){
    __shared__ __align__(16) unsigned short Abuf[2*2*128*64];   // 64 KiB
    __shared__ __align__(16) unsigned short Bbuf[2*2*128*64];   // 64 KiB
    const int tid = threadIdx.x, w = tid >> 6, lane = tid & 63;
    const int wr = w >> 2, wc = w & 3;                 // 2 x 4 wave grid
    const int bid = blockIdx.x;
    const int swz = (bid & 7)*64 + (bid >> 3);         // XCD-aware (512 % 8 == 0, bijective)
    const int m0 = (swz >> 3)*256, n0 = (swz & 7)*256;

    // ---- stage source: linear LDS dest, inverse-swizzled global source (rule #21)
    const int c0   = w*128 + lane;                     // chunk index within unit
    const int row0 = c0 >> 3;                          // 0..127
    const int swz8 = ((lane & 7) ^ (lane >> 3))*8;     // swizzled col-chunk * 8 elems
    const unsigned short* Asrc = A  + (size_t)(m0 + row0)*Dq + swz8;
    const unsigned short* Bsrc = Bw + (size_t)(n0 + row0)*Dq + swz8;

    // ---- ds_read offsets (ushort), read-side XOR swizzle: chunk ^= row&7
    const int r16 = lane & 15, kg = lane >> 4;
    const int cswz0 = ((kg    ) ^ (r16 & 7))*8;        // ks=0 global chunks 0..3
    const int cswz1 = ((kg + 4) ^ (r16 & 7))*8;        // ks=1 global chunks 4..7
    const int aBase = wr*8192 + r16*64;
    const int bBase = (wc >> 1)*8192 + (wc & 1)*4096 + r16*64;

    f4_t acc[8][4];
#pragma unroll
    for (int i=0;i<8;++i)
#pragma unroll
        for (int j=0;j<4;++j) acc[i][j] = (f4_t){0.f,0.f,0.f,0.f};

    bf8_t aE[4], aO[4], aE2[4], aO2[4], bE[4], bO[4];

    // ---- prologue: tile 0 (4 units) + (1,B,h0); keep only that in flight
    STG(Abuf, Asrc, 0, 0, 0);     // (0,A,h0)
    STG(Abuf, Asrc, 0, 1, 0);     // (0,A,h1)
    STG(Bbuf, Bsrc, 0, 0, 0);     // (0,B,h0)
    STG(Bbuf, Bsrc, 0, 1, 0);     // (0,B,h1)
    STG(Bbuf, Bsrc, 1, 0, 64);    // (1,B,h0)
    asm volatile("s_waitcnt vmcnt(2)" ::: "memory");
    __builtin_amdgcn_s_barrier();
    __builtin_amdgcn_sched_barrier(0);

    // ---- main loop: tiles 0..13
    for (int t = 0; t < 14; ++t){
        const int par = t & 1, npar = par ^ 1;
        const int kc1 = (t+1)*64, kc2 = (t+2)*64;

        // R1: reads for ph1+ph2; stage (t+1,A,h0) + (t+1,A,h1)
        LDA4(aE, 0, cswz0, par);
        LDB4(bE, cswz0, par);
        LDA4(aO, 4, cswz0, par);
        STG(Abuf, Asrc, npar, 0, kc1);
        STG(Abuf, Asrc, npar, 1, kc1);
        BAR(); MMQ(aE, bE, 0);

        // R2: reads for ph3; stage (t+1,B,h1)
        LDA4(aE2, 0, cswz1, par);
        LDB4(bO, cswz1, par);
        STG(Bbuf, Bsrc, npar, 1, kc1);
        BAR(); MMQ(aO, bE, 4);

        // R3: reads for ph4
        LDA4(aO2, 4, cswz1, par);
        BAR(); MMQ(aE2, bO, 0);

        // R4: drain tile t+1's units; full fence (the one true hazard boundary);
        //     stage (t+2,B,h0) into parity par after the fence
        asm volatile("s_waitcnt vmcnt(0)" ::: "memory");
        BARF();
        STG(Bbuf, Bsrc, par, 0, kc2);
        MMQ(aO2, bO, 4);
    }

    // ---- tile 14 (par=0): stage tile 15's remaining units, full drain at R4
    {
        const int par = 0, npar = 1, kc1 = 960;
        LDA4(aE, 0, cswz0, par);
        LDB4(bE, cswz0, par);
        LDA4(aO, 4, cswz0, par);
        STG(Abuf, Asrc, npar, 0, kc1);
        STG(Abuf, Asrc, npar, 1, kc1);
        BAR(); MMQ(aE, bE, 0);

        LDA4(aE2, 0, cswz1, par);
        LDB4(bO, cswz1, par);
        STG(Bbuf, Bsrc, npar, 1, kc1);
        BAR(); MMQ(aO, bE, 4);

        LDA4(aO2, 4, cswz1, par);
        BAR(); MMQ(aE2, bO, 0);

        asm volatile("s_waitcnt vmcnt(0)" ::: "memory");
        BARF();
        MMQ(aO2, bO, 4);
    }

    // ---- tile 15 (par=1): compute-only, no barriers needed
    {
        const int par = 1;
        LDA4(aE, 0, cswz0, par);
        LDB4(bE, cswz0, par);
        MMQ(aE, bE, 0);
        LDA4(aO, 4, cswz0, par);
        MMQ(aO, bE, 4);
        LDA4(aE2, 0, cswz1, par);
        LDB4(bO, cswz1, par);
        MMQ(aE2, bO, 0);
        LDA4(aO2, 4, cswz1, par);
        MMQ(aO2, bO, 4);
    }

    // ---- C write (bf16), verified C/D layout: col=lane&15, row=(lane>>4)*4+q
#pragma unroll
    for (int mi=0;mi<8;++mi){
#pragma unroll
        for (int nj=0;nj<4;++nj){
            const int col = n0 + wc*64 + nj*16 + r16;
            const int rb  = m0 + wr*128 + mi*16 + (lane >> 4)*4;
#pragma unroll
            for (int q=0;q<4;++q)
                zqv[(size_t)(rb+q)*NCOL + col] = f2bf(acc[mi][nj][q]);
        }
    }
}

#undef STG
#undef RDA
#undef RDB
#undef LDA4
#undef LDB4
#undef BAR
#undef BARF
#undef MMQ

// ---------------- G / M_cov / C_v partial sums + per-chunk max||z||^2 ----------------
__global__ __launch_bounds__(256) void k_cov(const unsigned short* __restrict__ zqv,
                                             const float* __restrict__ mask,
                                             float* __restrict__ part){
    __shared__ float Zs[65*32];
    __shared__ float Vs[64*64];
    __shared__ float Msk[66];
    __shared__ float sMx[64];
    const int tid = threadIdx.x, w = tid >> 6, lane = tid & 63;
    const int c = blockIdx.x, bh = blockIdx.y, b = bh >> 4, h = bh & 15;
    const unsigned short* zb = zqv + (size_t)b*Tq*NCOL + h*32;
    const unsigned short* vb = zqv + (size_t)b*Tq*NCOL + 1024 + h*64;
    const float* mb = mask + (size_t)b*Tq;

    const bool isC = lane >= 32;
    const bool isM = (lane >= 16) && (lane < 32);
    const int li = isC ? (lane - 32) : (lane & 15);
    const int i0 = (li >> 2)*8, j0 = (li & 3)*8;
    const float* Xb = isC ? (Vs + i0) : (Zs + 32 + i0);
    const int xst = isC ? 64 : 32;
    const float* Yb = isM ? (Zs + j0) : (Zs + 32 + j0);
    const int slotbase = isC ? (2048 + i0*32 + j0) : ((isM ? 1024 : 0) + i0*32 + j0);

    float acc[8][8];
#pragma unroll
    for (int i=0;i<8;++i)
#pragma unroll
        for (int j=0;j<8;++j) acc[i][j] = 0.f;
    float mxl = 0.f;

    for (int t0 = c*512; t0 < c*512 + 512; t0 += 64){
        __syncthreads();
        for (int i = tid; i < 520; i += 256){
            int r = i >> 3, cc = (i & 7)*4;
            int t = t0 - 1 + r;
            float4 o;
            if (t >= 0){
                us4_t u = *(const us4_t*)(zb + (size_t)t*NCOL + cc);
                o.x = bf2f(u.x); o.y = bf2f(u.y); o.z = bf2f(u.z); o.w = bf2f(u.w);
            } else { o.x=0.f; o.y=0.f; o.z=0.f; o.w=0.f; }
            *(float4*)&Zs[r*32 + cc] = o;
        }
        for (int i = tid; i < 1024; i += 256){
            int rr = i >> 4, cc = (i & 15)*4;
            us4_t u = *(const us4_t*)(vb + (size_t)(t0 + rr)*NCOL + cc);
            float4 o; o.x=bf2f(u.x); o.y=bf2f(u.y); o.z=bf2f(u.z); o.w=bf2f(u.w);
            *(float4*)&Vs[rr*64 + cc] = o;
        }
        if (tid < 65){ int t = t0 - 1 + tid; Msk[tid] = (t >= 0) ? mb[t] : 0.f; }
        __syncthreads();
        if (tid < 64){
            const float4* pr = (const float4*)&Zs[(tid+1)*32];
            float s = 0.f;
#pragma unroll
            for (int q=0;q<8;++q){ float4 v = pr[q]; s += v.x*v.x + v.y*v.y + v.z*v.z + v.w*v.w; }
            mxl = fmaxf(mxl, s);
        }
#pragma unroll 2
        for (int tt = w; tt < 64; tt += 4){
            const float mt = Msk[tt+1], mp = Msk[tt];
            // every accumulated term carries a factor of mt (m2=mt^2, al=mt*mp):
            // skipping mt==0 is exact, and the branch is wave-uniform (tt wave-uniform)
            if (mt == 0.f) continue;
            const float m2 = mt*mt, al = mt*mp;
            const float wgt = isM ? (al*al) : m2;
            const float* xp = Xb + tt*xst;
            const float* yp = Yb + tt*32;
            float4 x0 = *(const float4*)xp, x1 = *(const float4*)(xp + 4);
            float4 y0 = *(const float4*)yp, y1 = *(const float4*)(yp + 4);
            float xs[8] = {x0.x*wgt, x0.y*wgt, x0.z*wgt, x0.w*wgt,
                           x1.x*wgt, x1.y*wgt, x1.z*wgt, x1.w*wgt};
            float ys[8] = {y0.x, y0.y, y0.z, y0.w, y1.x, y1.y, y1.z, y1.w};
#pragma unroll
            for (int i=0;i<8;++i)
#pragma unroll
                for (int j=0;j<8;++j) acc[i][j] += xs[i]*ys[j];
        }
    }
    // cross-wave reduce in LDS (reuse Vs: 4096 floats)
    float* Acc = Vs;
    __syncthreads();
    if (tid < 64) sMx[tid] = mxl;
#pragma unroll
    for (int r = 0; r < 4; ++r){
        if (w == r){
            if (r == 0){
#pragma unroll
                for (int i=0;i<8;++i)
#pragma unroll
                    for (int j=0;j<8;++j) Acc[slotbase + i*32 + j] = acc[i][j];
            } else {
#pragma unroll
                for (int i=0;i<8;++i)
#pragma unroll
                    for (int j=0;j<8;++j) Acc[slotbase + i*32 + j] += acc[i][j];
            }
        }
        __syncthreads();
    }
    float* dst = part + ((size_t)c*64 + bh)*PSTRIDE;
    for (int i = tid; i < 4096; i += 256) dst[i] = Acc[i];
    if (tid == 0){
        float m = 0.f;
#pragma unroll
        for (int q=0;q<64;++q) m = fmaxf(m, sMx[q]);
        dst[4096] = m;
    }
}

// ---------------- per-(b,h) fp32 solver (no Cholesky):
// Gi = G^-1 (Gauss-Jordan), P = M Gi, Q = Gi P, sigma^2 = lam_max(M^T Q) via power iter,
// E = eta/mn * s^2 * C (Q P),  s = gam/max(sigma,1); E stored bf16 ----------------
__global__ __launch_bounds__(256) void k_solve(const float* __restrict__ part,
                                               const float* __restrict__ eta_p,
                                               const float* __restrict__ gam_p,
                                               unsigned short* __restrict__ Ebf){
    __shared__ float sM[1024], sC[2048], sGi[1024], sP[1024], sQ[1024], sT[1024];
    __shared__ float sAug[32*66];
    __shared__ float sv[32], su[32], sw[32], ssc[4];
    const int tid = threadIdx.x, bh = blockIdx.x;
    const size_t pb = (size_t)bh*PSTRIDE;

    // max over chunk maxes (redundant per-thread, broadcast loads)
    float mxx = 0.f;
#pragma unroll
    for (int c = 0; c < 8; ++c) mxx = fmaxf(mxx, part[((size_t)c*64)*PSTRIDE + pb + 4096]);
    const float mn = fmaxf(sqrtf(mxx), 1e-6f);
    const float i1 = 1.f/mn, i2 = i1*i1;

    for (int i = tid; i < 1024; i += 256){
        float a0 = 0.f, a1 = 0.f;
        for (int c = 0; c < 8; ++c){
            const float* p = part + ((size_t)c*64)*PSTRIDE + pb;
            a0 += p[i]; a1 += p[1024 + i];
        }
        sT[i] = a0; sM[i] = a1*i2;
    }
    for (int i = tid; i < 2048; i += 256){
        float a = 0.f;
        for (int c = 0; c < 8; ++c) a += part[((size_t)c*64)*PSTRIDE + pb + 2048 + i];
        sC[i] = a*i1;
    }
    __syncthreads();
    // Aug = [G_sym + ridge | I]
    for (int i = tid; i < 1024; i += 256){
        int r = i >> 5, s = i & 31;
        float g = 0.5f*(sT[i] + sT[s*32 + r])*i2 + (r == s ? RIDGEC : 0.f);
        sAug[r*66 + s] = g;
        sAug[r*66 + 32 + s] = (r == s) ? 1.f : 0.f;
    }
    __syncthreads();
    // Gauss-Jordan (SPD, no pivoting)
    const int gi = tid >> 3, gj0 = (tid & 7)*8;
    for (int p = 0; p < 32; ++p){
        float pivd = sAug[p*66 + p];
        float f    = sAug[gi*66 + p];
        float rp[8];
#pragma unroll
        for (int jj = 0; jj < 8; ++jj) rp[jj] = sAug[p*66 + gj0 + jj];
        __syncthreads();
        float pinv = 1.f/pivd;
        if (gi == p){
#pragma unroll
            for (int jj = 0; jj < 8; ++jj) sAug[p*66 + gj0 + jj] = rp[jj]*pinv;
        } else {
            float fp = f*pinv;
#pragma unroll
            for (int jj = 0; jj < 8; ++jj) sAug[gi*66 + gj0 + jj] -= fp*rp[jj];
        }
        __syncthreads();
    }
    for (int i = tid; i < 1024; i += 256){
        int r = i >> 5, s = i & 31;
        sGi[i] = sAug[r*66 + 32 + s];
    }
    __syncthreads();
    // P = M @ Gi   (left-row preload, float4 broadcast on right)
    {
        const int r = tid >> 3, s0 = (tid & 7)*4;
        float lrow[32];
#pragma unroll
        for (int q = 0; q < 8; ++q) *(float4*)&lrow[q*4] = *(const float4*)&sM[r*32 + q*4];
        float4 a = (float4){0.f,0.f,0.f,0.f};
        for (int k = 0; k < 32; ++k){
            float4 bb = *(const float4*)&sGi[k*32 + s0];
            a.x += lrow[k]*bb.x; a.y += lrow[k]*bb.y; a.z += lrow[k]*bb.z; a.w += lrow[k]*bb.w;
        }
        *(float4*)&sP[r*32 + s0] = a;
    }
    __syncthreads();
    // Q = Gi @ P
    {
        const int r = tid >> 3, s0 = (tid & 7)*4;
        float lrow[32];
#pragma unroll
        for (int q = 0; q < 8; ++q) *(float4*)&lrow[q*4] = *(const float4*)&sGi[r*32 + q*4];
        float4 a = (float4){0.f,0.f,0.f,0.f};
        for (int k = 0; k < 32; ++k){
            float4 bb = *(const float4*)&sP[k*32 + s0];
            a.x += lrow[k]*bb.x; a.y += lrow[k]*bb.y; a.z += lrow[k]*bb.z; a.w += lrow[k]*bb.w;
        }
        *(float4*)&sQ[r*32 + s0] = a;
    }
    __syncthreads();
    // power iteration: v <- normalize(M^T (Q v)), 6 iters
    if (tid < 32) sv[tid] = 0.17677669529663687f;
    __syncthreads();
    for (int it = 0; it < 6; ++it){
        if (tid < 32){ float a = 0.f; for (int k = 0; k < 32; ++k) a += sQ[tid*32+k]*sv[k]; su[tid] = a; }
        __syncthreads();
        if (tid < 32){ float a = 0.f; for (int k = 0; k < 32; ++k) a += sM[k*32+tid]*su[k]; sw[tid] = a; }
        __syncthreads();
        if (tid < 32){
            float n2 = 0.f;
#pragma unroll
            for (int k = 0; k < 32; ++k) n2 += sw[k]*sw[k];
            sv[tid] = sw[tid] * (1.f/fmaxf(sqrtf(n2), 1e-8f));
        }
        __syncthreads();
    }
    if (tid < 32){ float a = 0.f; for (int k = 0; k < 32; ++k) a += sQ[tid*32+k]*sv[k]; su[tid] = a; }
    __syncthreads();
    if (tid < 32){ float a = 0.f; for (int k = 0; k < 32; ++k) a += sM[k*32+tid]*su[k]; sw[tid] = a; }
    __syncthreads();
    if (tid == 0){
        float n2 = 0.f;
        for (int k = 0; k < 32; ++k) n2 += sw[k]*sw[k];
        float sigma = sqrtf(sqrtf(n2));          // ||Wv|| = sigma^2
        float gam = fminf(fmaxf(gam_p[0], 1.f), 1.5f);
        float s = gam/fmaxf(sigma, 1.f);
        ssc[0] = eta_p[0]*i1*s*s;
    }
    __syncthreads();
    // T = Q @ P
    {
        const int r = tid >> 3, s0 = (tid & 7)*4;
        float lrow[32];
#pragma unroll
        for (int q = 0; q < 8; ++q) *(float4*)&lrow[q*4] = *(const float4*)&sQ[r*32 + q*4];
        float4 a = (float4){0.f,0.f,0.f,0.f};
        for (int k = 0; k < 32; ++k){
            float4 bb = *(const float4*)&sP[k*32 + s0];
            a.x += lrow[k]*bb.x; a.y += lrow[k]*bb.y; a.z += lrow[k]*bb.z; a.w += lrow[k]*bb.w;
        }
        *(float4*)&sT[r*32 + s0] = a;
    }
    __syncthreads();
    // E = esc * C @ T  (64x32 @ 32x32), stored bf16 row-major (p x r)
    {
        const float esc = ssc[0];
        const int r = tid >> 2, s0 = (tid & 3)*8;
        float lrow[32];
#pragma unroll
        for (int q = 0; q < 8; ++q) *(float4*)&lrow[q*4] = *(const float4*)&sC[r*32 + q*4];
        float4 a0 = (float4){0.f,0.f,0.f,0.f}, a1 = (float4){0.f,0.f,0.f,0.f};
        for (int k = 0; k < 32; ++k){
            float4 b0 = *(const float4*)&sT[k*32 + s0];
            float4 b1 = *(const float4*)&sT[k*32 + s0 + 4];
            a0.x += lrow[k]*b0.x; a0.y += lrow[k]*b0.y; a0.z += lrow[k]*b0.z; a0.w += lrow[k]*b0.w;
            a1.x += lrow[k]*b1.x; a1.y += lrow[k]*b1.y; a1.z += lrow[k]*b1.z; a1.w += lrow[k]*b1.w;
        }
        us4_t o0, o1;
        o0.x=f2bf(a0.x*esc); o0.y=f2bf(a0.y*esc); o0.z=f2bf(a0.z*esc); o0.w=f2bf(a0.w*esc);
        o1.x=f2bf(a1.x*esc); o1.y=f2bf(a1.y*esc); o1.z=f2bf(a1.z*esc); o1.w=f2bf(a1.w*esc);
        *(us4_t*)&Ebf[(size_t)bh*2048 + r*32 + s0]     = o0;
        *(us4_t*)&Ebf[(size_t)bh*2048 + r*32 + s0 + 4] = o1;
    }
}

// ---------------- out[t,p] = sum_r zq[t,r] * E[p,r]  via MFMA (A=zq rows, B=E rows) ----------------
__global__ __launch_bounds__(256) void k_outm(const unsigned short* __restrict__ zqv,
                                              const unsigned short* __restrict__ Ebf,
                                              float* __restrict__ out){
    __shared__ __align__(16) unsigned short Es[2048];
    const int tid = threadIdx.x, w = tid >> 6, lane = tid & 63;
    const int bh = blockIdx.y, b = bh >> 4, h = bh & 15;
    // stage E (64 p x 32 r bf16 = 4096 B)
    ((float4*)Es)[tid & 255] = ((const float4*)(Ebf + (size_t)bh*2048))[tid & 255];
    __syncthreads();

    const int row16 = lane & 15, klo = (lane >> 4)*8;
    const int t0 = blockIdx.x*128 + w*32;
    const unsigned short* zq = zqv + ((size_t)b*Tq + t0 + row16)*NCOL + 512 + h*32 + klo;
    bf8_t aF0 = *(const bf8_t*)zq;
    bf8_t aF1 = *(const bf8_t*)(zq + (size_t)16*NCOL);

    bf8_t bF[4];
#pragma unroll
    for (int j=0;j<4;++j) bF[j] = *(const bf8_t*)&Es[(j*16 + row16)*32 + klo];

    f4_t acc[2][4];
#pragma unroll
    for (int i=0;i<2;++i)
#pragma unroll
        for (int j=0;j<4;++j) acc[i][j] = (f4_t){0.f,0.f,0.f,0.f};
#pragma unroll
    for (int j=0;j<4;++j){
        acc[0][j] = __builtin_amdgcn_mfma_f32_16x16x32_bf16(aF0, bF[j], acc[0][j], 0, 0, 0);
        acc[1][j] = __builtin_amdgcn_mfma_f32_16x16x32_bf16(aF1, bF[j], acc[1][j], 0, 0, 0);
    }
    const int rbase = (lane >> 4)*4;
#pragma unroll
    for (int half=0; half<2; ++half){
#pragma unroll
        for (int j=0;j<4;++j){
            int col = h*64 + j*16 + row16;
#pragma unroll
            for (int q=0;q<4;++q){
                int t = t0 + half*16 + rbase + q;
                out[((size_t)b*Tq + t)*1024 + col] = acc[half][j][q];
            }
        }
    }
}

extern "C" void kernel_launch(void* const* d_in, const int* in_sizes, int n_in,
                              void* d_out, int out_size, void* d_ws, size_t ws_size,
                              hipStream_t stream) {
    const float* h    = (const float*)d_in[0];
    const float* mask = (const float*)d_in[1];
    const float* Wk   = (const float*)d_in[2];
    const float* Wq   = (const float*)d_in[3];
    const float* Wv   = (const float*)d_in[4];
    const float* eta  = (const float*)d_in[5];
    const float* gam  = (const float*)d_in[6];
    float* out = (float*)d_out;

    char* ws = (char*)d_ws;
    unsigned short* hbf = (unsigned short*)(ws);                       // 33,554,432
    unsigned short* wbf = (unsigned short*)(ws + 33554432);            //  4,194,304
    unsigned short* zqv = (unsigned short*)(ws + 37748736);            // 67,108,864
    float*          part= (float*)         (ws + 104857600);           //  8,404,992
    unsigned short* Ebf = (unsigned short*)(ws + 113262592);           //    262,144

    k_prep <<<18432, 256, 0, stream>>>(h, Wk, Wq, Wv, hbf, wbf);
    k_gemm <<<dim3(512), 512, 0, stream>>>(hbf, wbf, zqv);
    k_cov  <<<dim3(8, 64), 256, 0, stream>>>(zqv, mask, part);
    k_solve<<<64, 256, 0, stream>>>(part, eta, gam, Ebf);
    k_outm <<<dim3(32, 64), 256, 0, stream>>>(zqv, Ebf, out);
}